// Round 2
// baseline (438.307 us; speedup 1.0000x reference)
//
#include <hip/hip_runtime.h>

// PointConv (kernel=stride=2x2, pad=0, grouping=C): per-location GEMM
//   out_l(32x256) = P_l(32x256) @ W_l(256x256) + bias[:,l]
// B=32, C=64, H=W=64, L=1024, n=256. fp32 in/out, bf16 MFMA inside.
// Memory-bound (256MB weight stream; roofline ~55us).
// R3 (resubmit; prior run was an infra failure, not a kernel failure):
// W LDS slab + per-slab barriers removed. Each weight element feeds
// exactly one lane's B-fragment (k=quad*8+j, p=wv*64+nt*16+col), so load
// W directly in fragment layout: per-lane strided dwords (4x64B fully-
// consumed segments per instr), register double-buffer, zero K-loop
// barriers -> 12 independent waves/CU keep ~96KB in flight (Little's law
// needs ~9KB/CU for 6.3TB/s). Prior bulk-sync slab structure had ~13%
// load duty cycle = the measured 0.86TB/s.

#define B_  32
#define C_  64
#define H_  64
#define W_  64
#define L_  1024
#define N_  256
#define SA  264   // A pitch (ushorts): 256+8

typedef __bf16 bf16x8 __attribute__((ext_vector_type(8)));
typedef float  f32x4  __attribute__((ext_vector_type(4)));

__device__ __forceinline__ unsigned short f2bf(float f) {
  unsigned int u = __builtin_bit_cast(unsigned int, f);
  u += 0x7FFFu + ((u >> 16) & 1u);          // RNE
  return (unsigned short)(u >> 16);
}

__global__ __launch_bounds__(256, 3) void pointconv_kernel(
    const float* __restrict__ x, const float* __restrict__ wgt,
    const float* __restrict__ bias, float* __restrict__ out) {
  __shared__ unsigned short A[B_ * SA];     // patches bf16 [b][n]

  const int bid = blockIdx.x;
  // XCD swizzle: consecutive-pw blocks co-resident on one XCD (x/out L2 merge)
  const int l  = ((bid & 7) << 7) | (bid >> 3);
  const int ph = l >> 5, pw = l & 31;
  const int h0 = ph * 2, w0 = pw * 2;
  const int tid = threadIdx.x;

  const float* __restrict__ wl = wgt + (size_t)l * (N_ * N_);

  const int lane = tid & 63;
  const int wv   = tid >> 6;      // wave owns p in [wv*64, wv*64+64)
  const int col  = lane & 15;
  const int quad = lane >> 4;

  // Per-lane W base in B-fragment layout: row quad*8 (+j, +32*s), col wv*64+col (+nt*16)
  const float* __restrict__ wp = wl + (quad * 8) * N_ + wv * 64 + col;

  float rb0[4][8], rb1[4][8];     // [nt][j] double buffer, fully static-indexed

  // ---- prologue: issue slab 0 loads first (deepest latency)
#pragma unroll
  for (int nt = 0; nt < 4; ++nt)
#pragma unroll
    for (int j = 0; j < 8; ++j)
      rb0[nt][j] = wp[j * N_ + nt * 16];

  // ---- Phase 1: unfold x[b, c, 2ph+kh, 2pw+kw] -> A[b][n = c*4 + kh*2 + kw]
  {
    const int b  = tid & 31;
    const int c0 = tid >> 5;
#pragma unroll
    for (int i = 0; i < 8; ++i) {
      const int c = c0 + i * 8;
      const float* px = x + (((b * C_ + c) * H_ + h0) * W_ + w0);
      float2 v0 = *(const float2*)px;
      float2 v1 = *(const float2*)(px + W_);
      ushort4 q;
      q.x = f2bf(v0.x); q.y = f2bf(v0.y);
      q.z = f2bf(v1.x); q.w = f2bf(v1.y);
      *(ushort4*)&A[b * SA + c * 4] = q;
    }
  }

  // ---- bias init (C/D: col=lane&15 -> p, row=quad*4+reg -> b)
  f32x4 acc[2][4];
#pragma unroll
  for (int nt = 0; nt < 4; ++nt) {
    const int p = wv * 64 + nt * 16 + col;
    const float bv = bias[p * L_ + l];
#pragma unroll
    for (int mt = 0; mt < 2; ++mt) {
      acc[mt][nt][0] = bv; acc[mt][nt][1] = bv;
      acc[mt][nt][2] = bv; acc[mt][nt][3] = bv;
    }
  }

  __syncthreads();   // A ready — the only barrier in the kernel

  // ---- K-loop: 8 slabs of 32, fully unrolled, barrier-free
#pragma unroll
  for (int s = 0; s < 8; ++s) {
    // prefetch slab s+1 into the other buffer (in flight across MFMAs below)
    if (s < 7) {
      const float* np = wp + (s + 1) * 32 * N_;
      if (s & 1) {
#pragma unroll
        for (int nt = 0; nt < 4; ++nt)
#pragma unroll
          for (int j = 0; j < 8; ++j)
            rb0[nt][j] = np[j * N_ + nt * 16];
      } else {
#pragma unroll
        for (int nt = 0; nt < 4; ++nt)
#pragma unroll
          for (int j = 0; j < 8; ++j)
            rb1[nt][j] = np[j * N_ + nt * 16];
      }
    }

    // A-frags: A[m=mt*16+col][k = s*32 + quad*8 + j] -- ds_read_b128
    bf16x8 af[2];
#pragma unroll
    for (int mt = 0; mt < 2; ++mt)
      af[mt] = *(const bf16x8*)&A[(mt * 16 + col) * SA + s * 32 + quad * 8];

#pragma unroll
    for (int nt = 0; nt < 4; ++nt) {
      union { unsigned short u[8]; bf16x8 v; } bu;
#pragma unroll
      for (int j = 0; j < 8; ++j)
        bu.u[j] = f2bf((s & 1) ? rb1[nt][j] : rb0[nt][j]);
#pragma unroll
      for (int mt = 0; mt < 2; ++mt)
        acc[mt][nt] = __builtin_amdgcn_mfma_f32_16x16x32_bf16(
            af[mt], bu.v, acc[mt][nt], 0, 0, 0);
    }
  }

  // ---- Epilogue: fold. p -> (c=p>>2, kh=(p>>1)&1, kw=p&1)
#pragma unroll
  for (int mt = 0; mt < 2; ++mt) {
#pragma unroll
    for (int nt = 0; nt < 4; ++nt) {
      const int p  = wv * 64 + nt * 16 + col;
      const int c  = p >> 2;
      const int kh = (p >> 1) & 1;
      const int kw = p & 1;
      float* po = out + (((c * H_) + h0 + kh) * W_ + w0 + kw);
#pragma unroll
      for (int r = 0; r < 4; ++r) {
        const int b = mt * 16 + quad * 4 + r;
        po[b * (C_ * H_ * W_)] = acc[mt][nt][r];
      }
    }
  }
}

extern "C" void kernel_launch(void* const* d_in, const int* in_sizes, int n_in,
                              void* d_out, int out_size, void* d_ws, size_t ws_size,
                              hipStream_t stream) {
  const float* x    = (const float*)d_in[0];
  const float* wgt  = (const float*)d_in[1];
  const float* bias = (const float*)d_in[2];
  float* out = (float*)d_out;
  pointconv_kernel<<<dim3(L_), dim3(256), 0, stream>>>(x, wgt, bias, out);
}

// Round 3
// 428.349 us; speedup vs baseline: 1.0232x; 1.0232x over previous
//
#include <hip/hip_runtime.h>

// PointConv (kernel=stride=2x2, pad=0, grouping=C): per-location GEMM
//   out_l(32x256) = P_l(32x256) @ W_l(256x256) + bias[:,l]
// B=32, C=64, H=W=64, L=1024, n=256. fp32 in/out, bf16 MFMA inside.
// Memory-bound (256MB weight stream; roofline ~50us incl. current write amp).
// R4: R3's barrier-free register double-buffer was DEFEATED by the compiler
// (VGPR_Count=52 < the 64 needed for rb0+rb1 => loads were sunk next to
// their converts, ~1 load/wave in flight, 1.86 TB/s). Fix: pin the schedule
// with sched_barrier(0) fences around the per-slab {issue} and {compute}
// regions so slab s+1's 32 loads stay issued before slab s's converts
// (auto-waitcnt then lands at vmcnt(~32): full pipeline, ~96KB/CU in
// flight vs ~10KB needed).

#define B_  32
#define C_  64
#define H_  64
#define W_  64
#define L_  1024
#define N_  256
#define SA  264   // A pitch (ushorts): 256+8

typedef __bf16 bf16x8 __attribute__((ext_vector_type(8)));
typedef float  f32x4  __attribute__((ext_vector_type(4)));

__device__ __forceinline__ unsigned short f2bf(float f) {
  unsigned int u = __builtin_bit_cast(unsigned int, f);
  u += 0x7FFFu + ((u >> 16) & 1u);          // RNE
  return (unsigned short)(u >> 16);
}

__global__ __launch_bounds__(256, 3) void pointconv_kernel(
    const float* __restrict__ x, const float* __restrict__ wgt,
    const float* __restrict__ bias, float* __restrict__ out) {
  __shared__ unsigned short A[B_ * SA];     // patches bf16 [b][n]

  const int bid = blockIdx.x;
  // XCD swizzle: consecutive-pw blocks co-resident on one XCD (x/out L2 merge)
  const int l  = ((bid & 7) << 7) | (bid >> 3);
  const int ph = l >> 5, pw = l & 31;
  const int h0 = ph * 2, w0 = pw * 2;
  const int tid = threadIdx.x;

  const float* __restrict__ wl = wgt + (size_t)l * (N_ * N_);

  const int lane = tid & 63;
  const int wv   = tid >> 6;      // wave owns p in [wv*64, wv*64+64)
  const int col  = lane & 15;
  const int quad = lane >> 4;

  // Per-lane W base in B-fragment layout: row quad*8 (+j, +32*s), col wv*64+col (+nt*16)
  const float* __restrict__ wp = wl + (quad * 8) * N_ + wv * 64 + col;

  float rb0[4][8], rb1[4][8];     // [nt][j] double buffer, fully static-indexed

  // ---- prologue: issue slab 0 loads first (deepest latency)
#pragma unroll
  for (int nt = 0; nt < 4; ++nt)
#pragma unroll
    for (int j = 0; j < 8; ++j)
      rb0[nt][j] = wp[j * N_ + nt * 16];
  __builtin_amdgcn_sched_barrier(0);   // keep slab-0 issue ahead of everything

  // ---- Phase 1: unfold x[b, c, 2ph+kh, 2pw+kw] -> A[b][n = c*4 + kh*2 + kw]
  {
    const int b  = tid & 31;
    const int c0 = tid >> 5;
#pragma unroll
    for (int i = 0; i < 8; ++i) {
      const int c = c0 + i * 8;
      const float* px = x + (((b * C_ + c) * H_ + h0) * W_ + w0);
      float2 v0 = *(const float2*)px;
      float2 v1 = *(const float2*)(px + W_);
      ushort4 q;
      q.x = f2bf(v0.x); q.y = f2bf(v0.y);
      q.z = f2bf(v1.x); q.w = f2bf(v1.y);
      *(ushort4*)&A[b * SA + c * 4] = q;
    }
  }

  // ---- bias init (C/D: col=lane&15 -> p, row=quad*4+reg -> b)
  f32x4 acc[2][4];
#pragma unroll
  for (int nt = 0; nt < 4; ++nt) {
    const int p = wv * 64 + nt * 16 + col;
    const float bv = bias[p * L_ + l];
#pragma unroll
    for (int mt = 0; mt < 2; ++mt) {
      acc[mt][nt][0] = bv; acc[mt][nt][1] = bv;
      acc[mt][nt][2] = bv; acc[mt][nt][3] = bv;
    }
  }

  __syncthreads();   // A ready — the only barrier in the kernel

  // ---- K-loop: 8 slabs of 32, fully unrolled, barrier-free.
  // sched_barrier(0) fences pin {issue next slab} strictly before
  // {compute current slab} so the register double-buffer survives
  // instruction scheduling (R3 lesson: without fences the loads sink
  // to their uses and the pipeline vanishes).
#pragma unroll
  for (int s = 0; s < 8; ++s) {
    // ---- issue region: prefetch slab s+1 into the other buffer
    if (s < 7) {
      const float* np = wp + (s + 1) * 32 * N_;
      if (s & 1) {
#pragma unroll
        for (int nt = 0; nt < 4; ++nt)
#pragma unroll
          for (int j = 0; j < 8; ++j)
            rb0[nt][j] = np[j * N_ + nt * 16];
      } else {
#pragma unroll
        for (int nt = 0; nt < 4; ++nt)
#pragma unroll
          for (int j = 0; j < 8; ++j)
            rb1[nt][j] = np[j * N_ + nt * 16];
      }
    }
    __builtin_amdgcn_sched_barrier(0);   // loads stay issued here

    // ---- compute region: consume slab s (waits vmcnt(~32) at first cvt)
    // A-frags: A[m=mt*16+col][k = s*32 + quad*8 + j] -- ds_read_b128
    bf16x8 af[2];
#pragma unroll
    for (int mt = 0; mt < 2; ++mt)
      af[mt] = *(const bf16x8*)&A[(mt * 16 + col) * SA + s * 32 + quad * 8];

#pragma unroll
    for (int nt = 0; nt < 4; ++nt) {
      union { unsigned short u[8]; bf16x8 v; } bu;
#pragma unroll
      for (int j = 0; j < 8; ++j)
        bu.u[j] = f2bf((s & 1) ? rb1[nt][j] : rb0[nt][j]);
#pragma unroll
      for (int mt = 0; mt < 2; ++mt)
        acc[mt][nt] = __builtin_amdgcn_mfma_f32_16x16x32_bf16(
            af[mt], bu.v, acc[mt][nt], 0, 0, 0);
    }
    __builtin_amdgcn_sched_barrier(0);   // compute can't leak into next issue
  }

  // ---- Epilogue: fold. p -> (c=p>>2, kh=(p>>1)&1, kw=p&1)
#pragma unroll
  for (int mt = 0; mt < 2; ++mt) {
#pragma unroll
    for (int nt = 0; nt < 4; ++nt) {
      const int p  = wv * 64 + nt * 16 + col;
      const int c  = p >> 2;
      const int kh = (p >> 1) & 1;
      const int kw = p & 1;
      float* po = out + (((c * H_) + h0 + kh) * W_ + w0 + kw);
#pragma unroll
      for (int r = 0; r < 4; ++r) {
        const int b = mt * 16 + quad * 4 + r;
        po[b * (C_ * H_ * W_)] = acc[mt][nt][r];
      }
    }
  }
}

extern "C" void kernel_launch(void* const* d_in, const int* in_sizes, int n_in,
                              void* d_out, int out_size, void* d_ws, size_t ws_size,
                              hipStream_t stream) {
  const float* x    = (const float*)d_in[0];
  const float* wgt  = (const float*)d_in[1];
  const float* bias = (const float*)d_in[2];
  float* out = (float*)d_out;
  pointconv_kernel<<<dim3(L_), dim3(256), 0, stream>>>(x, wgt, bias, out);
}

// Round 4
// 427.904 us; speedup vs baseline: 1.0243x; 1.0010x over previous
//
#include <hip/hip_runtime.h>

// PointConv (kernel=stride=2x2, pad=0, grouping=C): per-location GEMM
//   out_l(32x256) = P_l(32x256) @ W_l(256x256) + bias[:,l]
// B=32, C=64, H=W=64, L=1024, n=256. fp32 in/out, bf16 MFMA inside.
// Memory-bound (256MB weight stream; ~50us floor at current write amp).
// R5: three schedules (bulk-sync LDS, sunk regs, fenced regs) all hit the
// same ~150us / 2TB/s wall -> compiler cannot be made to keep 32 VGPR-dest
// loads in flight (R3: VGPR=52; R4 fences: +10us only). Structural fix per
// T3/T4: global_load_lds DMA (in-flight depth lives in the HW VMEM queue,
// not VGPRs) + counted vmcnt(24) waits + raw s_barrier, quad-buffered
// 32KB fp32 slabs (3 slabs = 96KB/CU always in flight). W fragment reads
// from LDS use a 64B XOR source-pre-swizzle (DMA dest must stay linear)
// -> 2-way banked (free). 1 block/CU (148KB LDS) by design.

#define B_  32
#define C_  64
#define H_  64
#define W_  64
#define L_  1024
#define N_  256
#define SA  264   // A pitch (ushorts): 256+8
#define NBUF 4    // W slab quad-buffer

typedef __bf16 bf16x8 __attribute__((ext_vector_type(8)));
typedef float  f32x4  __attribute__((ext_vector_type(4)));

__device__ __forceinline__ unsigned short f2bf(float f) {
  unsigned int u = __builtin_bit_cast(unsigned int, f);
  u += 0x7FFFu + ((u >> 16) & 1u);          // RNE
  return (unsigned short)(u >> 16);
}

__device__ __forceinline__ void async_ld16(const float* g, float* l) {
  __builtin_amdgcn_global_load_lds(
      (const __attribute__((address_space(1))) void*)g,
      (__attribute__((address_space(3))) void*)l, 16, 0, 0);
}

__global__ __launch_bounds__(256, 1) void pointconv_kernel(
    const float* __restrict__ x, const float* __restrict__ wgt,
    const float* __restrict__ bias, float* __restrict__ out) {
  __shared__ __align__(16)  unsigned short A[B_ * SA];   // patches bf16 [b][n]
  __shared__ __align__(128) float Wb[NBUF][32 * N_];     // W slabs fp32 (DMA dest)

  const int bid = blockIdx.x;
  // XCD swizzle: consecutive-pw blocks co-resident on one XCD
  const int l  = ((bid & 7) << 7) | (bid >> 3);
  const int ph = l >> 5, pw = l & 31;
  const int h0 = ph * 2, w0 = pw * 2;
  const int tid  = threadIdx.x;
  const int lane = tid & 63;
  const int wv   = tid >> 6;      // wave owns p in [wv*64, wv*64+64)
  const int col  = lane & 15;
  const int quad = lane >> 4;

  const float* __restrict__ wl = wgt + (size_t)l * (N_ * N_);
  // DMA source: wave wv stages slab rows wv*8..wv*8+7. 64B XOR pre-swizzle
  // on the SOURCE (flag = slab_row>>3 = wv here) so LDS[f] = src[f ^ (flag<<4)].
  const float* wsrc = wl + (wv * 8) * N_ + ((lane * 4) ^ ((wv & 1) << 4));

  // ---- issue x-unfold + bias loads FIRST (so their waits don't drain DMAs)
  const int ub  = tid & 31;       // b
  const int uc0 = tid >> 5;       // c0
  float2 xv[8][2];
#pragma unroll
  for (int i = 0; i < 8; ++i) {
    const int c = uc0 + i * 8;
    const float* px = x + (((ub * C_ + c) * H_ + h0) * W_ + w0);
    xv[i][0] = *(const float2*)px;
    xv[i][1] = *(const float2*)(px + W_);
  }
  float bv[4];
#pragma unroll
  for (int nt = 0; nt < 4; ++nt)
    bv[nt] = bias[(wv * 64 + nt * 16 + col) * L_ + l];
  __builtin_amdgcn_sched_barrier(0);

  // ---- DMA slabs 0..3 (8 instrs/wave/slab, 1KB contiguous each)
#pragma unroll
  for (int ss = 0; ss < NBUF; ++ss)
#pragma unroll
    for (int i = 0; i < 8; ++i)
      async_ld16(wsrc + (ss * 32 + i) * N_, &Wb[ss][(wv * 8 + i) * N_]);
  __builtin_amdgcn_sched_barrier(0);

  // ---- unfold -> A (bf16), n = c*4 + kh*2 + kw
#pragma unroll
  for (int i = 0; i < 8; ++i) {
    const int c = uc0 + i * 8;
    ushort4 q;
    q.x = f2bf(xv[i][0].x); q.y = f2bf(xv[i][0].y);
    q.z = f2bf(xv[i][1].x); q.w = f2bf(xv[i][1].y);
    *(ushort4*)&A[ub * SA + c * 4] = q;
  }

  // ---- bias init (C/D: col -> p, quad*4+reg -> b)
  f32x4 acc[2][4];
#pragma unroll
  for (int nt = 0; nt < 4; ++nt)
#pragma unroll
    for (int mt = 0; mt < 2; ++mt) {
      acc[mt][nt][0] = bv[nt]; acc[mt][nt][1] = bv[nt];
      acc[mt][nt][2] = bv[nt]; acc[mt][nt][3] = bv[nt];
    }

  // A visible to all waves WITHOUT draining the DMA queue (no __syncthreads!)
  asm volatile("s_waitcnt lgkmcnt(0)" ::: "memory");
  __builtin_amdgcn_s_barrier();

  // ---- K-steps: wait own slab-T DMAs (counted, never early-drain), barrier,
  // consume (LDS fp32 -> bf16 frags -> MFMA), barrier, re-issue into freed buf.
#define KSTEP(T, VM)                                                           \
  {                                                                            \
    asm volatile("s_waitcnt vmcnt(" #VM ")" ::: "memory");                     \
    __builtin_amdgcn_sched_barrier(0);                                         \
    __builtin_amdgcn_s_barrier();                                              \
    bf16x8 af0 = *(const bf16x8*)&A[col * SA + (T) * 32 + quad * 8];           \
    bf16x8 af1 = *(const bf16x8*)&A[(16 + col) * SA + (T) * 32 + quad * 8];    \
    const float* wb = &Wb[(T) & (NBUF - 1)][0];                                \
    _Pragma("unroll")                                                          \
    for (int nt = 0; nt < 4; ++nt) {                                           \
      const int pp = (wv * 64 + nt * 16 + col) ^ ((quad & 1) << 4);            \
      union { unsigned short u[8]; bf16x8 v; } bu;                             \
      _Pragma("unroll")                                                        \
      for (int j = 0; j < 8; ++j)                                              \
        bu.u[j] = f2bf(wb[(quad * 8 + j) * N_ + pp]);                          \
      acc[0][nt] = __builtin_amdgcn_mfma_f32_16x16x32_bf16(af0, bu.v,          \
                                                           acc[0][nt], 0, 0, 0); \
      acc[1][nt] = __builtin_amdgcn_mfma_f32_16x16x32_bf16(af1, bu.v,          \
                                                           acc[1][nt], 0, 0, 0); \
    }                                                                          \
    __builtin_amdgcn_sched_barrier(0);                                         \
    __builtin_amdgcn_s_barrier();                                              \
    if ((T) + NBUF < 8) {                                                      \
      _Pragma("unroll")                                                        \
      for (int i = 0; i < 8; ++i)                                              \
        async_ld16(wsrc + (((T) + NBUF) * 32 + i) * N_,                        \
                   &Wb[(T) & (NBUF - 1)][(wv * 8 + i) * N_]);                  \
    }                                                                          \
  }

  KSTEP(0, 24)
  KSTEP(1, 24)
  KSTEP(2, 24)
  KSTEP(3, 24)
  KSTEP(4, 24)
  KSTEP(5, 16)
  KSTEP(6, 8)
  KSTEP(7, 0)
#undef KSTEP

  // ---- Epilogue: fold. p -> (c=p>>2, kh=(p>>1)&1, kw=p&1)
#pragma unroll
  for (int mt = 0; mt < 2; ++mt) {
#pragma unroll
    for (int nt = 0; nt < 4; ++nt) {
      const int p  = wv * 64 + nt * 16 + col;
      const int c  = p >> 2;
      const int kh = (p >> 1) & 1;
      const int kw = p & 1;
      float* po = out + (((c * H_) + h0 + kh) * W_ + w0 + kw);
#pragma unroll
      for (int r = 0; r < 4; ++r) {
        const int b = mt * 16 + quad * 4 + r;
        po[b * (C_ * H_ * W_)] = acc[mt][nt][r];
      }
    }
  }
}

extern "C" void kernel_launch(void* const* d_in, const int* in_sizes, int n_in,
                              void* d_out, int out_size, void* d_ws, size_t ws_size,
                              hipStream_t stream) {
  const float* x    = (const float*)d_in[0];
  const float* wgt  = (const float*)d_in[1];
  const float* bias = (const float*)d_in[2];
  float* out = (float*)d_out;
  pointconv_kernel<<<dim3(L_), dim3(256), 0, stream>>>(x, wgt, bias, out);
}